// Round 12
// baseline (101.135 us; speedup 1.0000x reference)
//
#include <hip/hip_runtime.h>
#include <math.h>

typedef _Float16 f16x8  __attribute__((ext_vector_type(8)));    // MFMA A/B operand (4 VGPRs)
typedef _Float16 h2v    __attribute__((ext_vector_type(2)));
typedef float    f32x16 __attribute__((ext_vector_type(16)));   // MFMA C/D operand (32x32)
typedef float    f32x4  __attribute__((ext_vector_type(4)));
typedef __fp16   h2a    __attribute__((ext_vector_type(2)));    // cvt_pkrtz result
typedef unsigned u32x4  __attribute__((ext_vector_type(4)));

#define WS    10
#define HID   32
#define BDIM  256
#define NWAVE 4
#define GN    32                  // points per group = MFMA N
#define T_LEN 4096
#define NGRP  (T_LEN / GN)        // 128 groups/row; 32 per wave; 16 ILP2-iters

__device__ inline unsigned pack2u(float a, float b) {
    h2a t = __builtin_amdgcn_cvt_pkrtz(a, b);   // a -> low16, b -> high16
    return __builtin_bit_cast(unsigned, t);
}
__device__ inline unsigned relu2(unsigned u) {  // v_pk_max_f16 with 0
    h2v x = __builtin_bit_cast(h2v, u);
    h2v z = {(_Float16)0.0f, (_Float16)0.0f};
    return __builtin_bit_cast(unsigned, __builtin_elementwise_max(x, z));
}

__device__ inline void load_win(const float* __restrict__ rptr, int t, int hi,
                                float e2[2], float v6[6]) {
    // lane window bytes contiguous: 8B @ ws+8*hi = (e0,e1 | e8,e9),
    // 24B @ ws+2 = e2..e7 (hi=1: in-bounds discard). 4B-aligned only.
    const int ws = (t >= WS) ? (t - WS) : 0;    // head points (t<10) reuse window 0
    __builtin_memcpy(e2, &rptr[ws + 8 * hi], 8);
    __builtin_memcpy(v6, &rptr[ws + 2], 24);
}

// (256,2): 256-reg budget so BOTH chains' MFMA C/D vectors live in arch
// VGPRs — no v_accvgpr spill traffic (r11's hidden serializer: at (256,3)
// the 2nd chain spilled to AGPRs and the move-chain serialized the ILP).
// 2 waves/SIMD x 2 chains = 4 independent chains per SIMD.
__global__ __launch_bounds__(BDIM, 2)
void hurst_ilp2v(const float* __restrict__ returns,
                 const float* __restrict__ W1, const float* __restrict__ b1,
                 const float* __restrict__ W2, const float* __restrict__ b2,
                 const float* __restrict__ W3, const float* __restrict__ b3,
                 float* __restrict__ out)
{
    const int tid  = threadIdx.x;
    const int wid  = tid >> 6;
    const int lane = tid & 63;
    const int n    = lane & 31;    // MFMA m (A-row) / n (B/C col)
    const int hi   = lane >> 5;    // k-half (A/B) / row-half (C/D)

    // ---- bias C-operands in C-layout: row(r)=(r&3)+8(r>>2)+4hi ----
    f32x16 b1v, b2v;
    #pragma unroll
    for (int i = 0; i < 4; ++i) {
        const f32x4 v1 = ((const f32x4*)b1)[2 * i + hi];
        const f32x4 v2 = ((const f32x4*)b2)[2 * i + hi];
        #pragma unroll
        for (int o = 0; o < 4; ++o) {
            b1v[4 * i + o] = v1[o];
            b2v[4 * i + o] = v2[o];
        }
    }
    const float corr = b3[0] - b2[4 * hi];   // undoes b2v[0] riding L3's C-init

    // ---- A-frags; phi(k)=swap(bit2,bit3) absorbs the C->B layout permutation
    // between stages (verified r6-r11, absmax 1.95e-3) ----
    f16x8 a1, a2lo, a2hi, a3lo, a3hi;
    #pragma unroll
    for (int jj = 0; jj < 8; ++jj) {
        const int k  = 8 * hi + jj;
        a1[jj] = (k < WS) ? (_Float16)W1[k * HID + n] : (_Float16)0.0f;   // W1^T, K 10->16 pad
        const int kf = (k & 3) | ((k & 4) << 1) | ((k & 8) >> 1);         // phi: swap bits 2<->3
        a2lo[jj] = (_Float16)W2[kf * HID + n];
        a2hi[jj] = (_Float16)W2[(16 + kf) * HID + n];
        a3lo[jj] = (_Float16)W3[kf];          // broadcast over m
        a3hi[jj] = (_Float16)W3[16 + kf];
    }

    const float* rptr = returns + (size_t)blockIdx.x * T_LEN;
    float*       optr = out     + (size_t)blockIdx.x * T_LEN;

    // ---- two chains per iteration (groups g, g+NWAVE), prefetched 1 ahead ----
    float e2c[2][2], v6c[2][6];
    load_win(rptr, wid * GN + n,           hi, e2c[0], v6c[0]);
    load_win(rptr, (wid + NWAVE) * GN + n, hi, e2c[1], v6c[1]);

    for (int g = wid; g < NGRP; g += 2 * NWAVE) {
        const int gp = (g + 2 * NWAVE < NGRP) ? (g + 2 * NWAVE) : g;
        float e2n[2][2], v6n[2][6];
        load_win(rptr, gp * GN + n,           hi, e2n[0], v6n[0]);
        load_win(rptr, (gp + NWAVE) * GN + n, hi, e2n[1], v6n[1]);

        // ---- stage-interleaved: unroll over chain index at every stage ----
        f16x8 xb[2];
        #pragma unroll
        for (int c = 0; c < 2; ++c) {
            u32x4 xu;
            xu[0] = pack2u(e2c[c][0], e2c[c][1]);
            xu[1] = hi ? 0u : pack2u(v6c[c][0], v6c[c][1]);
            xu[2] = hi ? 0u : pack2u(v6c[c][2], v6c[c][3]);
            xu[3] = hi ? 0u : pack2u(v6c[c][4], v6c[c][5]);
            xb[c] = __builtin_bit_cast(f16x8, xu);
        }

        f32x16 d1[2];
        #pragma unroll
        for (int c = 0; c < 2; ++c)
            d1[c] = __builtin_amdgcn_mfma_f32_32x32x16_f16(a1, xb[c], b1v, 0, 0, 0);

        u32x4 p1lo[2], p1hi[2];
        #pragma unroll
        for (int c = 0; c < 2; ++c)
            #pragma unroll
            for (int i = 0; i < 4; ++i) {
                p1lo[c][i] = relu2(pack2u(d1[c][2 * i],     d1[c][2 * i + 1]));
                p1hi[c][i] = relu2(pack2u(d1[c][8 + 2 * i], d1[c][9 + 2 * i]));
            }

        f32x16 d2[2];
        #pragma unroll
        for (int c = 0; c < 2; ++c)
            d2[c] = __builtin_amdgcn_mfma_f32_32x32x16_f16(
                        a2lo, __builtin_bit_cast(f16x8, p1lo[c]), b2v, 0, 0, 0);
        #pragma unroll
        for (int c = 0; c < 2; ++c)
            d2[c] = __builtin_amdgcn_mfma_f32_32x32x16_f16(
                        a2hi, __builtin_bit_cast(f16x8, p1hi[c]), d2[c], 0, 0, 0);

        u32x4 p2lo[2], p2hi[2];
        #pragma unroll
        for (int c = 0; c < 2; ++c)
            #pragma unroll
            for (int i = 0; i < 4; ++i) {
                p2lo[c][i] = relu2(pack2u(d2[c][2 * i],     d2[c][2 * i + 1]));
                p2hi[c][i] = relu2(pack2u(d2[c][8 + 2 * i], d2[c][9 + 2 * i]));
            }

        f32x16 d3[2];
        #pragma unroll
        for (int c = 0; c < 2; ++c)
            d3[c] = __builtin_amdgcn_mfma_f32_32x32x16_f16(
                        a3lo, __builtin_bit_cast(f16x8, p2lo[c]), b2v, 0, 0, 0);
        #pragma unroll
        for (int c = 0; c < 2; ++c)
            d3[c] = __builtin_amdgcn_mfma_f32_32x32x16_f16(
                        a3hi, __builtin_bit_cast(f16x8, p2hi[c]), d3[c], 0, 0, 0);

        float o[2];
        #pragma unroll
        for (int c = 0; c < 2; ++c)
            o[c] = 0.5f * __builtin_amdgcn_rcpf(1.0f + __expf(-(d3[c][0] + corr)));

        if (hi == 0) {
            optr[g * GN + n]           = o[0];
            optr[(g + NWAVE) * GN + n] = o[1];
        }

        #pragma unroll
        for (int c = 0; c < 2; ++c) {
            #pragma unroll
            for (int i = 0; i < 2; ++i) e2c[c][i] = e2n[c][i];
            #pragma unroll
            for (int i = 0; i < 6; ++i) v6c[c][i] = v6n[c][i];
        }
    }
}

extern "C" void kernel_launch(void* const* d_in, const int* in_sizes, int n_in,
                              void* d_out, int out_size, void* d_ws, size_t ws_size,
                              hipStream_t stream) {
    const float* returns = (const float*)d_in[0];
    const float* W1      = (const float*)d_in[1];
    const float* b1      = (const float*)d_in[2];
    const float* W2      = (const float*)d_in[3];
    const float* b2      = (const float*)d_in[4];
    const float* W3      = (const float*)d_in[5];
    const float* b3      = (const float*)d_in[6];
    float* out = (float*)d_out;

    const int B = out_size / T_LEN;   // 1024

    dim3 grid(B, 1, 1);               // one block per batch row
    dim3 block(BDIM, 1, 1);
    hurst_ilp2v<<<grid, block, 0, stream>>>(returns, W1, b1, W2, b2, W3, b3, out);
}

// Round 13
// 98.673 us; speedup vs baseline: 1.0250x; 1.0250x over previous
//
#include <hip/hip_runtime.h>
#include <math.h>

typedef _Float16 f16x8  __attribute__((ext_vector_type(8)));    // MFMA A/B operand (4 VGPRs)
typedef _Float16 h2v    __attribute__((ext_vector_type(2)));
typedef float    f32x16 __attribute__((ext_vector_type(16)));   // MFMA C/D operand (32x32)
typedef float    f32x4  __attribute__((ext_vector_type(4)));
typedef __fp16   h2a    __attribute__((ext_vector_type(2)));    // cvt_pkrtz result
typedef unsigned u32x4  __attribute__((ext_vector_type(4)));

#define WS    10
#define HID   32
#define BDIM  256
#define NWAVE 4
#define GN    32                  // points per group = MFMA N
#define T_LEN 4096
#define NGRP  (T_LEN / GN)        // 128 groups per row
#define NIT   16                  // iters/wave: 2 group-indices x 2 rows = 4 chains/iter

__device__ inline unsigned pack2u(float a, float b) {
    h2a t = __builtin_amdgcn_cvt_pkrtz(a, b);   // a -> low16, b -> high16
    return __builtin_bit_cast(unsigned, t);
}
__device__ inline unsigned relu2(unsigned u) {  // v_pk_max_f16 with 0
    h2v x = __builtin_bit_cast(h2v, u);
    h2v z = {(_Float16)0.0f, (_Float16)0.0f};
    return __builtin_bit_cast(unsigned, __builtin_elementwise_max(x, z));
}

// grid 512 x 2 rows/block at (256,2): exactly 2 blocks/CU, ALL co-resident,
// single round, zero tail. ILP=4 chains/iter (2 rows x 2 group-indices;
// rows share t/ws address math). 2 waves x 4 chains = 8 chains/SIMD.
__global__ __launch_bounds__(BDIM, 2)
void hurst_ilp4(const float* __restrict__ returns,
                const float* __restrict__ W1, const float* __restrict__ b1,
                const float* __restrict__ W2, const float* __restrict__ b2,
                const float* __restrict__ W3, const float* __restrict__ b3,
                float* __restrict__ out)
{
    const int tid  = threadIdx.x;
    const int wid  = tid >> 6;
    const int lane = tid & 63;
    const int n    = lane & 31;    // MFMA m (A-row) / n (B/C col)
    const int hi   = lane >> 5;    // k-half (A/B) / row-half (C/D)

    // ---- bias C-operands in C-layout: row(r)=(r&3)+8(r>>2)+4hi ----
    f32x16 b1v, b2v;
    #pragma unroll
    for (int i = 0; i < 4; ++i) {
        const f32x4 v1 = ((const f32x4*)b1)[2 * i + hi];
        const f32x4 v2 = ((const f32x4*)b2)[2 * i + hi];
        #pragma unroll
        for (int o = 0; o < 4; ++o) {
            b1v[4 * i + o] = v1[o];
            b2v[4 * i + o] = v2[o];
        }
    }
    const float corr = b3[0] - b2[4 * hi];   // undoes b2v[0] riding L3's C-init

    // ---- A-frags; phi(k)=swap(bit2,bit3) absorbs the C->B layout permutation
    // between stages (verified r6-r12, absmax 1.95e-3) ----
    f16x8 a1, a2lo, a2hi, a3lo, a3hi;
    #pragma unroll
    for (int jj = 0; jj < 8; ++jj) {
        const int k  = 8 * hi + jj;
        a1[jj] = (k < WS) ? (_Float16)W1[k * HID + n] : (_Float16)0.0f;   // W1^T, K 10->16 pad
        const int kf = (k & 3) | ((k & 4) << 1) | ((k & 8) >> 1);         // phi: swap bits 2<->3
        a2lo[jj] = (_Float16)W2[kf * HID + n];
        a2hi[jj] = (_Float16)W2[(16 + kf) * HID + n];
        a3lo[jj] = (_Float16)W3[kf];          // broadcast over m
        a3hi[jj] = (_Float16)W3[16 + kf];
    }

    const float* rA = returns + (size_t)(2 * blockIdx.x) * T_LEN;
    const float* rB = rA + T_LEN;
    float*       oA = out + (size_t)(2 * blockIdx.x) * T_LEN;
    float*       oB = oA + T_LEN;

    for (int i = 0; i < NIT; ++i) {
        // two group-indices; chains: (A,g1)(B,g1)(A,g2)(B,g2)
        const int g1  = wid + 8 * i;
        const int g2  = g1 + 4;
        const int t1  = g1 * GN + n;
        const int t2  = g2 * GN + n;
        const int ws1 = (t1 >= WS) ? (t1 - WS) : 0;   // head points reuse window 0
        const int ws2 = (t2 >= WS) ? (t2 - WS) : 0;

        // ---- loads: lane window bytes contiguous; 8B @ ws+8*hi = (e0,e1|e8,e9),
        // 24B @ ws+2 = e2..e7 (hi=1: in-bounds discard). 4B-aligned only. ----
        float e2[4][2], v6[4][6];
        __builtin_memcpy(e2[0], rA + ws1 + 8 * hi, 8);  __builtin_memcpy(v6[0], rA + ws1 + 2, 24);
        __builtin_memcpy(e2[1], rB + ws1 + 8 * hi, 8);  __builtin_memcpy(v6[1], rB + ws1 + 2, 24);
        __builtin_memcpy(e2[2], rA + ws2 + 8 * hi, 8);  __builtin_memcpy(v6[2], rA + ws2 + 2, 24);
        __builtin_memcpy(e2[3], rB + ws2 + 8 * hi, 8);  __builtin_memcpy(v6[3], rB + ws2 + 2, 24);

        // ---- stage-interleaved 4-chain MLP ----
        f16x8 xb[4];
        #pragma unroll
        for (int c = 0; c < 4; ++c) {
            u32x4 xu;
            xu[0] = pack2u(e2[c][0], e2[c][1]);
            xu[1] = hi ? 0u : pack2u(v6[c][0], v6[c][1]);
            xu[2] = hi ? 0u : pack2u(v6[c][2], v6[c][3]);
            xu[3] = hi ? 0u : pack2u(v6[c][4], v6[c][5]);
            xb[c] = __builtin_bit_cast(f16x8, xu);
        }

        f32x16 d1[4];
        #pragma unroll
        for (int c = 0; c < 4; ++c)
            d1[c] = __builtin_amdgcn_mfma_f32_32x32x16_f16(a1, xb[c], b1v, 0, 0, 0);

        u32x4 p1lo[4], p1hi[4];
        #pragma unroll
        for (int c = 0; c < 4; ++c)
            #pragma unroll
            for (int q = 0; q < 4; ++q) {
                p1lo[c][q] = relu2(pack2u(d1[c][2 * q],     d1[c][2 * q + 1]));
                p1hi[c][q] = relu2(pack2u(d1[c][8 + 2 * q], d1[c][9 + 2 * q]));
            }

        f32x16 d2[4];
        #pragma unroll
        for (int c = 0; c < 4; ++c)
            d2[c] = __builtin_amdgcn_mfma_f32_32x32x16_f16(
                        a2lo, __builtin_bit_cast(f16x8, p1lo[c]), b2v, 0, 0, 0);
        #pragma unroll
        for (int c = 0; c < 4; ++c)
            d2[c] = __builtin_amdgcn_mfma_f32_32x32x16_f16(
                        a2hi, __builtin_bit_cast(f16x8, p1hi[c]), d2[c], 0, 0, 0);

        u32x4 p2lo[4], p2hi[4];
        #pragma unroll
        for (int c = 0; c < 4; ++c)
            #pragma unroll
            for (int q = 0; q < 4; ++q) {
                p2lo[c][q] = relu2(pack2u(d2[c][2 * q],     d2[c][2 * q + 1]));
                p2hi[c][q] = relu2(pack2u(d2[c][8 + 2 * q], d2[c][9 + 2 * q]));
            }

        f32x16 d3[4];
        #pragma unroll
        for (int c = 0; c < 4; ++c)
            d3[c] = __builtin_amdgcn_mfma_f32_32x32x16_f16(
                        a3lo, __builtin_bit_cast(f16x8, p2lo[c]), b2v, 0, 0, 0);
        #pragma unroll
        for (int c = 0; c < 4; ++c)
            d3[c] = __builtin_amdgcn_mfma_f32_32x32x16_f16(
                        a3hi, __builtin_bit_cast(f16x8, p2hi[c]), d3[c], 0, 0, 0);

        float o[4];
        #pragma unroll
        for (int c = 0; c < 4; ++c)
            o[c] = 0.5f * __builtin_amdgcn_rcpf(1.0f + __expf(-(d3[c][0] + corr)));

        if (hi == 0) {
            oA[t1] = o[0];
            oB[t1] = o[1];
            oA[t2] = o[2];
            oB[t2] = o[3];
        }
    }
}

extern "C" void kernel_launch(void* const* d_in, const int* in_sizes, int n_in,
                              void* d_out, int out_size, void* d_ws, size_t ws_size,
                              hipStream_t stream) {
    const float* returns = (const float*)d_in[0];
    const float* W1      = (const float*)d_in[1];
    const float* b1      = (const float*)d_in[2];
    const float* W2      = (const float*)d_in[3];
    const float* b2      = (const float*)d_in[4];
    const float* W3      = (const float*)d_in[5];
    const float* b3      = (const float*)d_in[6];
    float* out = (float*)d_out;

    const int B = out_size / T_LEN;   // 1024

    dim3 grid(B / 2, 1, 1);           // 512 blocks x 2 rows: all co-resident, one round
    dim3 block(BDIM, 1, 1);
    hurst_ilp4<<<grid, block, 0, stream>>>(returns, W1, b1, W2, b2, W3, b3, out);
}